// Round 1
// baseline (1341.047 us; speedup 1.0000x reference)
//
#include <hip/hip_runtime.h>
#include <hip/hip_bf16.h>

// Problem dims
static const int kB = 128, kN = 49, kC = 2048, kD = 512, kE = 512, kV = 10000, kT = 20;

typedef __bf16 bf16x8 __attribute__((ext_vector_type(8)));
typedef float  f32x4v __attribute__((ext_vector_type(4)));
typedef _Float16 h8_t __attribute__((ext_vector_type(8)));
typedef unsigned short u16;
typedef unsigned int u32;

__device__ __forceinline__ float sigmoidf_(float x){ return 1.f/(1.f+expf(-x)); }
__device__ __forceinline__ u16 f2b(float x){ __hip_bfloat16 h = __float2bfloat16(x); return *(u16*)&h; }
__device__ __forceinline__ float bu2f(u32 u){ u32 w = u << 16; union{u32 u; float f;} c; c.u = w; return c.f; }

// ================= bf16 MFMA NT GEMM =================
// C[M,N] = act(A[M,K]@W[N,K]^T + bias + add1[m&a1mask]), fp32 acc.
// C (fp32) and Cbf (bf16) both optional.
#define TBM 128
#define TBN 128
#define TBK 32

__global__ __launch_bounds__(256) void gemm_bf16(
    const u16* __restrict__ A, int lda,
    const u16* __restrict__ W, int ldw,
    float* __restrict__ C, u16* __restrict__ Cbf, int ldc,
    int M, int N, int K,
    const float* __restrict__ bias,
    const float* __restrict__ add1, int ld1, int a1mask,
    int act)
{
    __shared__ __align__(16) u16 As[TBM*TBK];
    __shared__ __align__(16) u16 Bs[TBN*TBK];
    const int tid = threadIdx.x;
    const int bm = blockIdx.y * TBM;
    const int bn = blockIdx.x * TBN;
    const int wave = tid >> 6, lane = tid & 63;
    const int wm = (wave >> 1) * 64, wn = (wave & 1) * 64;
    const int lm = lane & 15, quad = lane >> 4;
    const int r = tid >> 2, koff = (tid & 3) * 8;
    f32x4v acc[4][4] = {};
    for (int k0 = 0; k0 < K; k0 += TBK) {
        #pragma unroll
        for (int h = 0; h < 2; ++h) {
            int row = r + h*64;
            bf16x8 av = {};
            int gm = bm + row;
            if (gm < M) av = *(const bf16x8*)(A + (size_t)gm*lda + k0 + koff);
            *(bf16x8*)&As[row*TBK + koff] = av;
            bf16x8 wv = {};
            int gn = bn + row;
            if (gn < N) wv = *(const bf16x8*)(W + (size_t)gn*ldw + k0 + koff);
            *(bf16x8*)&Bs[row*TBK + koff] = wv;
        }
        __syncthreads();
        bf16x8 afr[4], bfr[4];
        #pragma unroll
        for (int i = 0; i < 4; ++i) afr[i] = *(const bf16x8*)&As[(wm + i*16 + lm)*TBK + quad*8];
        #pragma unroll
        for (int j = 0; j < 4; ++j) bfr[j] = *(const bf16x8*)&Bs[(wn + j*16 + lm)*TBK + quad*8];
        #pragma unroll
        for (int i = 0; i < 4; ++i)
            #pragma unroll
            for (int j = 0; j < 4; ++j)
                acc[i][j] = __builtin_amdgcn_mfma_f32_16x16x32_bf16(afr[i], bfr[j], acc[i][j], 0, 0, 0);
        __syncthreads();
    }
    #pragma unroll
    for (int i = 0; i < 4; ++i) {
        int mbase = bm + wm + i*16 + quad*4;
        #pragma unroll
        for (int j = 0; j < 4; ++j) {
            int n = bn + wn + j*16 + lm;
            if (n >= N) continue;
            float bv = bias ? bias[n] : 0.f;
            #pragma unroll
            for (int rr2 = 0; rr2 < 4; ++rr2) {
                int m = mbase + rr2;
                if (m >= M) continue;
                float v = acc[i][j][rr2] + bv;
                if (add1) v += add1[(size_t)(m & a1mask)*ld1 + n];
                if (act == 1) v = fmaxf(v, 0.f);
                else if (act == 2) v = tanhf(v);
                if (C)   C[(size_t)m*ldc + n] = v;
                if (Cbf) Cbf[(size_t)m*ldc + n] = f2b(v);
            }
        }
    }
}

// ================= conversion / prep kernels =================
// fp32 [rows][src_ld] (first K cols) -> bf16 [rows][K]
__global__ __launch_bounds__(256) void cvt2d_k(const float* __restrict__ src, int src_ld, int K,
                                               int rows, u16* __restrict__ dst){
    int idx = blockIdx.x*256 + threadIdx.x;
    int kc8 = K >> 3;
    if (idx >= rows*kc8) return;
    int rr = idx / kc8, kc = idx - rr*kc8;
    const float* p = src + (size_t)rr*src_ld + kc*8;
    f32x4v f0 = *(const f32x4v*)p, f1 = *(const f32x4v*)(p+4);
    union { u16 u[8]; uint4 v; } pk;
    pk.u[0]=f2b(f0[0]); pk.u[1]=f2b(f0[1]); pk.u[2]=f2b(f0[2]); pk.u[3]=f2b(f0[3]);
    pk.u[4]=f2b(f1[0]); pk.u[5]=f2b(f1[1]); pk.u[6]=f2b(f1[2]); pk.u[7]=f2b(f1[3]);
    *(uint4*)(dst + (size_t)rr*K + kc*8) = pk.v;
}

// fp32 [rows][src_ld] (K=512) -> f16 interleaved [k/8][Ntot][8] at row offset n_off
__global__ __launch_bounds__(256) void cvt_il_k(const float* __restrict__ src, int src_ld,
                                                int rows, int n_off, int Ntot,
                                                _Float16* __restrict__ dst){
    int idx = blockIdx.x*256 + threadIdx.x;
    if (idx >= rows*64) return;
    int rr = idx >> 6, kc = idx & 63;
    const float* p = src + (size_t)rr*src_ld + kc*8;
    f32x4v f0 = *(const f32x4v*)p, f1 = *(const f32x4v*)(p+4);
    h8_t o;
    o[0]=(_Float16)f0[0]; o[1]=(_Float16)f0[1]; o[2]=(_Float16)f0[2]; o[3]=(_Float16)f0[3];
    o[4]=(_Float16)f1[0]; o[5]=(_Float16)f1[1]; o[6]=(_Float16)f1[2]; o[7]=(_Float16)f1[3];
    *(h8_t*)&dst[((size_t)kc*Ntot + n_off + rr)*8] = o;
}

// bias2560 = [bih+bhh (2048); 0 (512)]; bcat3 = [bb|bhi|bmi]
__global__ __launch_bounds__(256) void bias_prep_k(const float* bih, const float* bhh,
                                                   const float* bb, const float* bhi, const float* bmi,
                                                   float* bias2560, float* bcat3){
    int i = blockIdx.x*256 + threadIdx.x;
    if (i < 2048) bias2560[i] = bih[i] + bhh[i];
    else if (i < 2560) bias2560[i] = 0.f;
    else if (i < 4096){
        int j = i - 2560;
        bcat3[j] = (j < 512) ? bb[j] : (j < 1024 ? bhi[j-512] : bmi[j-1024]);
    }
}

__global__ __launch_bounds__(256) void mean_k(const float* __restrict__ img, u16* __restrict__ meanp){
    int idx = blockIdx.x*256 + threadIdx.x;       // B*C
    int b = idx >> 11, c = idx & (kC-1);
    const float* p = img + (size_t)b*kN*kC + c;
    float s = 0.f;
    #pragma unroll
    for (int n = 0; n < kN; ++n) s += p[(size_t)n*kC];
    meanp[idx] = f2b(s * (1.f/(float)kN));
}

// we[t*B+b][e] bf16
__global__ __launch_bounds__(256) void emb_gather_k(const int* __restrict__ target,
                                                    const float* __restrict__ emb,
                                                    u16* __restrict__ we){
    int idx = blockIdx.x*256 + threadIdx.x;       // T*B*E
    int e = idx & (kE-1);
    int rr = idx >> 9;                            // t*B + b
    int b = rr & 127, t = rr >> 7;
    float v = 0.f;
    if (t > 0){ int tok = target[b*kT + (t-1)]; v = emb[(size_t)tok*kE + e]; }
    we[idx] = f2b(v);
}

// ================= persistent per-batch LSTM recurrence (gates only) =================
// Only the true sequential dependence lives here: h -> gates -> (h2, m2).
// Everything downstream (H, s, attention, out) is deferred to batched GEMMs.
__device__ __forceinline__ float dot8f(h8_t a, h8_t b, float c){
    #pragma unroll
    for (int i = 0; i < 8; ++i) c = fmaf((float)a[i], (float)b[i], c);
    return c;
}

__global__ __launch_bounds__(512, 1) void scan_k(
    const float* __restrict__ initC,       // [128][1536] vg|h0|m0 (fp32)
    const float* __restrict__ xall,        // [20][128][2560]
    const _Float16* __restrict__ Wrec,     // il [64][2560][8]
    u16* __restrict__ h2_bf,               // [20*128][512] bf16 (row t*128+b)
    u16* __restrict__ gtv_bf)              // [20*128][512] bf16
{
    const int b = blockIdx.x, tid = threadIdx.x;
    __shared__ __align__(16) _Float16 sh[512];     // h (f16)

    sh[tid] = (_Float16)initC[(size_t)b*1536 + 512 + tid];
    float m_reg = initC[(size_t)b*1536 + 1024 + tid];
    __syncthreads();

    for (int t = 0; t < kT; ++t){
        // gates GEMV (thread tid -> outputs tid+512j, j=0..4)
        float acc[5];
        const float* xrow = xall + ((size_t)t*kB + b)*2560;
        #pragma unroll
        for (int j = 0; j < 5; ++j) acc[j] = xrow[tid + 512*j];
        for (int kc = 0; kc < 64; ++kc){
            h8_t hv = *(const h8_t*)&sh[kc*8];
            const _Float16* wb = Wrec + (size_t)kc*2560*8;
            #pragma unroll
            for (int j = 0; j < 5; ++j){
                h8_t wv = *(const h8_t*)&wb[(size_t)(tid + 512*j)*8];
                acc[j] = dot8f(hv, wv, acc[j]);
            }
        }
        // LSTM pointwise (thread-local)
        float i_g = sigmoidf_(acc[0]);
        float f_g = sigmoidf_(acc[1]);
        float g_g = tanhf(acc[2]);
        float o_g = sigmoidf_(acc[3]);
        m_reg = f_g*m_reg + i_g*g_g;
        float tm = tanhf(m_reg);
        float h2v = o_g*tm;
        float gtvv = sigmoidf_(acc[4])*tm;
        __syncthreads();                      // all reads of sh complete
        sh[tid] = (_Float16)h2v;
        size_t row = (size_t)t*kB + b;
        h2_bf[row*512 + tid] = f2b(h2v);
        gtv_bf[row*512 + tid] = f2b(gtvv);
        __syncthreads();
    }
}

// ================= batched attention kernel: one block per (t,b) row =================
// z[n] = sum_k tanh(zb[b][n][k]+gH[k])*wh[k];  z2 = sum_n tanh(sWs[n]+gH[n])*wh[n]
// alpha = softmax([z, z2]);  ctx = alpha[:49]@Vf[b] + alpha[49]*s;  Hc = H + ctx (bf16)
__global__ __launch_bounds__(256) void attn_k(
    const float* __restrict__ gH_all,      // [2560][49]
    const float* __restrict__ sWs_all,     // [2560][49]
    const float* __restrict__ H_all,       // [2560][512] fp32
    const float* __restrict__ s_all,       // [2560][512] fp32
    const u16* __restrict__ Vf_bf,         // [128*49][512] bf16
    const float* __restrict__ zbase,       // [128][49][49]
    const float* __restrict__ wh,          // [49]
    u16* __restrict__ Hc_bf,               // [2560][512] bf16
    float* __restrict__ attn_out)          // [128][20][49] fp32
{
    const int r = blockIdx.x, tid = threadIdx.x;   // r = t*128 + b
    const int b = r & 127, t = r >> 7;
    __shared__ float sgH[52], ssWs[52], swh[52], sz[52], salpha[52];

    if (tid < 49){
        sgH[tid]  = gH_all [(size_t)r*49 + tid];
        ssWs[tid] = sWs_all[(size_t)r*49 + tid];
        swh[tid]  = wh[tid];
    }
    __syncthreads();
    if (tid < 49){
        const float* zb = zbase + (size_t)b*2401 + (size_t)tid*49;
        float a = 0.f;
        #pragma unroll
        for (int k = 0; k < 49; ++k) a += tanhf(zb[k] + sgH[k]) * swh[k];
        sz[tid] = a;
    }
    if (tid == 64){
        float a = 0.f;
        #pragma unroll
        for (int k = 0; k < 49; ++k) a += tanhf(ssWs[k] + sgH[k]) * swh[k];
        sz[49] = a;
    }
    __syncthreads();
    // softmax over 50 on wave 0
    if (tid < 64){
        float val = (tid < 50) ? sz[tid] : -1e30f;
        float mx = val;
        #pragma unroll
        for (int o = 32; o > 0; o >>= 1) mx = fmaxf(mx, __shfl_xor(mx, o));
        float e = (tid < 50) ? __expf(val - mx) : 0.f;
        float ssum = e;
        #pragma unroll
        for (int o = 32; o > 0; o >>= 1) ssum += __shfl_xor(ssum, o);
        float a = e/ssum;
        if (tid < 50) salpha[tid] = a;
        if (tid < 49) attn_out[((size_t)b*kT + t)*kN + tid] = a;
    }
    __syncthreads();
    // ctx + Hc (coalesced across d)
    for (int d = tid; d < 512; d += 256){
        float a = salpha[49] * s_all[(size_t)r*512 + d];
        const u16* vf = Vf_bf + (size_t)b*49*512 + d;
        #pragma unroll
        for (int n = 0; n < 49; ++n) a = fmaf(salpha[n], bu2f(vf[(size_t)n*512]), a);
        Hc_bf[(size_t)r*512 + d] = f2b(H_all[(size_t)r*512 + d] + a);
    }
}

// ================= log-softmax: read bf16 logits row (t*128+b), write fp32 row (b*20+t) =================
__global__ __launch_bounds__(256) void logsoftmax_k(const u16* __restrict__ logits_bf,
                                                    float* __restrict__ out0)
{
    const int r = blockIdx.x, tid = threadIdx.x;   // r = b*20+t
    const int b = r / 20, t = r - b*20;
    const u16* L = logits_bf + (size_t)(t*kB + b)*kV;
    __shared__ float rm[256], rs[256];
    float m = -1e30f, s = 0.f;
    for (int c = tid; c < kV/8; c += 256){
        uint4 v = *(const uint4*)(L + c*8);
        u32 w[4] = {v.x, v.y, v.z, v.w};
        #pragma unroll
        for (int j = 0; j < 4; ++j){
            float x0 = bu2f(w[j] & 0xffff), x1 = bu2f(w[j] >> 16);
            float nm = fmaxf(m, fmaxf(x0, x1));
            s = s*__expf(m - nm) + __expf(x0 - nm) + __expf(x1 - nm);
            m = nm;
        }
    }
    rm[tid] = m; rs[tid] = s; __syncthreads();
    for (int st = 128; st > 0; st >>= 1){
        if (tid < st){
            float m2 = rm[tid + st], s2 = rs[tid + st];
            float nm = fmaxf(rm[tid], m2);
            rs[tid] = rs[tid]*__expf(rm[tid] - nm) + s2*__expf(m2 - nm);
            rm[tid] = nm;
        }
        __syncthreads();
    }
    float lse = rm[0] + logf(rs[0]);
    float* D = out0 + (size_t)r*kV;
    for (int c = tid; c < kV/8; c += 256){
        uint4 v = *(const uint4*)(L + c*8);
        u32 w[4] = {v.x, v.y, v.z, v.w};
        f32x4v o0, o1;
        o0[0]=bu2f(w[0]&0xffff)-lse; o0[1]=bu2f(w[0]>>16)-lse;
        o0[2]=bu2f(w[1]&0xffff)-lse; o0[3]=bu2f(w[1]>>16)-lse;
        o1[0]=bu2f(w[2]&0xffff)-lse; o1[1]=bu2f(w[2]>>16)-lse;
        o1[2]=bu2f(w[3]&0xffff)-lse; o1[3]=bu2f(w[3]>>16)-lse;
        *(f32x4v*)(D + c*8) = o0;
        *(f32x4v*)(D + c*8 + 4) = o1;
    }
}

extern "C" void kernel_launch(void* const* d_in, const int* in_sizes, int n_in,
                              void* d_out, int out_size, void* d_ws, size_t ws_size,
                              hipStream_t stream)
{
    const float* img   = (const float*)d_in[0];
    const int*   target= (const int*)  d_in[1];
    const float* emb   = (const float*)d_in[2];
    const float* Wa    = (const float*)d_in[3];
    const float* ba    = (const float*)d_in[4];
    const float* Wb    = (const float*)d_in[5];
    const float* bb    = (const float*)d_in[6];
    const float* Whi   = (const float*)d_in[7];
    const float* bhi   = (const float*)d_in[8];
    const float* Wmi   = (const float*)d_in[9];
    const float* bmi   = (const float*)d_in[10];
    const float* Wih   = (const float*)d_in[11];
    const float* bih   = (const float*)d_in[12];
    const float* Whh   = (const float*)d_in[13];
    const float* bhh   = (const float*)d_in[14];
    const float* Wv    = (const float*)d_in[15];
    const float* Wg    = (const float*)d_in[16];
    const float* wh    = (const float*)d_in[17];
    const float* W_H   = (const float*)d_in[18];
    const float* Wx    = (const float*)d_in[19];
    const float* Wh2   = (const float*)d_in[20];
    const float* Wsm   = (const float*)d_in[21];
    const float* Wc    = (const float*)d_in[22];
    const float* bc    = (const float*)d_in[23];
    const float* Wfc   = (const float*)d_in[24];
    const float* bfc   = (const float*)d_in[25];
    const float* Wp    = (const float*)d_in[26];
    const float* bp    = (const float*)d_in[27];
    (void)in_sizes; (void)n_in; (void)out_size; (void)ws_size;

    float* out0 = (float*)d_out;                       // [B*T, V] logprobs (row b*20+t)
    float* attn_out = out0 + (size_t)kB*kT*kV;         // [B, T, N]

    char* base = (char*)d_ws;
    size_t off = 0;
    auto alloc = [&](size_t bytes)->char*{
        char* p = base + off;
        off += ((bytes + 255) & ~(size_t)255);
        return p;
    };
    // fixed region
    u16* Wa_bf     = (u16*)alloc((size_t)kD*kC*2);
    u16* Winit_bf  = (u16*)alloc((size_t)1536*kC*2);
    u16* Wv_bf     = (u16*)alloc((size_t)kN*kD*2);
    u16* Wp_bf     = (u16*)alloc((size_t)kV*kD*2);
    u16* Wfirst_bf = (u16*)alloc((size_t)2560*512*2); // [Wih[:, :512]; Wx[:, :512]]
    u16* Wlast_bf  = (u16*)alloc((size_t)2560*512*2); // [Wih[:, 512:]; Wx[:, 512:]]
    _Float16* Wrec_il = (_Float16*)alloc((size_t)2560*512*2);
    u16* WH_bf     = (u16*)alloc((size_t)512*512*2);
    u16* Wc_bf     = (u16*)alloc((size_t)512*512*2);
    u16* Wg_bf     = (u16*)alloc((size_t)kN*512*2);
    u16* Ws_bf     = (u16*)alloc((size_t)kN*512*2);
    u16* Wfc_bf    = (u16*)alloc((size_t)512*512*2);
    float* bias2560 = (float*)alloc(2560*4);
    float* bcat3    = (float*)alloc(1536*4);
    u16* meanb_bf   = (u16*)alloc((size_t)kB*kC*2);
    float* initC    = (float*)alloc((size_t)kB*1536*4);
    u16* init_bf    = (u16*)alloc((size_t)kB*1536*2);
    u16* Vf_bf      = (u16*)alloc((size_t)kB*kN*kD*2);
    float* zbase    = (float*)alloc((size_t)kB*kN*kN*4);
    u16* we_bf      = (u16*)alloc((size_t)kT*kB*kE*2);
    float* gbase    = (float*)alloc((size_t)kB*2560*4);
    u16* outbf      = (u16*)alloc((size_t)kT*kB*kD*2);
    u16* h2_bf      = (u16*)alloc((size_t)kT*kB*kD*2);
    u16* gtv_bf     = (u16*)alloc((size_t)kT*kB*kD*2);

    // dynamic region, time-multiplexed:
    //  phase 1 (prep):       img_bf [0, 25.7MB) ; xall [25.7, 51.9MB)
    //  phase 2 (post-scan):  deferred-phase buffers alias img_bf region (img dead after Vf GEMM)
    //  phase 3 (logits):     logits_bf [0, 51.2MB) (all phase buffers dead after D-GEMM)
    char* dyn = base + off;
    u16* img_bf    = (u16*)dyn;
    float* xall    = (float*)(dyn + (((size_t)kB*kN*kC*2 + 255) & ~(size_t)255));
    u16* logits_bf = (u16*)dyn;
    {
        // nothing
    }
    size_t poff = 0;
    auto palloc = [&](size_t bytes)->char*{
        char* p = dyn + poff;
        poff += ((bytes + 255) & ~(size_t)255);
        return p;
    };
    float* H_all   = (float*)palloc((size_t)kT*kB*kD*4);
    float* s_all   = (float*)palloc((size_t)kT*kB*kD*4);
    u16*   H_bfb   = (u16*)  palloc((size_t)kT*kB*kD*2);
    u16*   s_bfb   = (u16*)  palloc((size_t)kT*kB*kD*2);
    float* gH_all  = (float*)palloc((size_t)kT*kB*kN*4);
    float* sWs_all = (float*)palloc((size_t)kT*kB*kN*4);
    u16*   Hc_bf   = (u16*)  palloc((size_t)kT*kB*kD*2);
    // total phase buffers ~19.4MB < img_bf's 25.7MB: no overlap with xall.

    auto G = [&](const u16* A, int lda, const u16* W, int ldw,
                 float* C, u16* Cbf, int ldc, int M, int N, int K,
                 const float* bias, const float* a1, int l1, int a1mask, int act){
        dim3 g((N + TBN - 1)/TBN, (M + TBM - 1)/TBM);
        gemm_bf16<<<g, 256, 0, stream>>>(A, lda, W, ldw, C, Cbf, ldc, M, N, K,
                                         bias, a1, l1, a1mask, act);
    };
    auto CV = [&](const float* src, int src_ld, int K, int rows, u16* dst){
        int n = rows*(K/8);
        cvt2d_k<<<(n + 255)/256, 256, 0, stream>>>(src, src_ld, K, rows, dst);
    };
    auto IL = [&](const float* src, int rows, int n_off, int Ntot, _Float16* dst){
        int n = rows*64;
        cvt_il_k<<<(n + 255)/256, 256, 0, stream>>>(src, 512, rows, n_off, Ntot, dst);
    };

    // ---- prep ----
    bias_prep_k<<<16, 256, 0, stream>>>(bih, bhh, bb, bhi, bmi, bias2560, bcat3);
    mean_k<<<kB*kC/256, 256, 0, stream>>>(img, meanb_bf);
    emb_gather_k<<<kT*kB*kE/256, 256, 0, stream>>>(target, emb, we_bf);
    CV(img, kC, kC, kB*kN, img_bf);
    CV(Wa,  kC, kC, kD, Wa_bf);
    CV(Wb,  kC, kC, kD, Winit_bf);
    CV(Whi, kC, kC, kD, Winit_bf + (size_t)512*kC);
    CV(Wmi, kC, kC, kD, Winit_bf + (size_t)1024*kC);
    CV(Wv,  kD, kD, kN, Wv_bf);
    CV(Wp,  kD, kD, kV, Wp_bf);
    CV(Wih,       1024, 512, 2048, Wfirst_bf);
    CV(Wx,        1024, 512, 512,  Wfirst_bf + (size_t)2048*512);
    CV(Wih + 512, 1024, 512, 2048, Wlast_bf);
    CV(Wx  + 512, 1024, 512, 512,  Wlast_bf + (size_t)2048*512);
    CV(W_H, 512, 512, 512, WH_bf);
    CV(Wc,  512, 512, 512, Wc_bf);
    CV(Wg,  512, 512, kN,  Wg_bf);
    CV(Wsm, 512, 512, kN,  Ws_bf);
    CV(Wfc, 512, 512, 512, Wfc_bf);
    IL(Whh, 2048, 0,    2560, Wrec_il);
    IL(Wh2, 512,  2048, 2560, Wrec_il);

    // ---- precompute GEMMs ----
    // [vg|h0|m0] = relu(mean @ [Wb;Whi;Wmi]^T + bcat3)
    G(meanb_bf, kC, Winit_bf, kC, initC, init_bf, 1536, kB, 1536, kC, bcat3, nullptr, 0, -1, 1);
    // Vf = relu(img @ Wa^T + ba)  (bf16 out only)
    G(img_bf, kC, Wa_bf, kC, nullptr, Vf_bf, kD, kB*kN, kD, kC, ba, nullptr, 0, -1, 1);
    // zbase = Vf @ Wv^T (fp32)
    G(Vf_bf, kD, Wv_bf, kD, zbase, nullptr, kN, kB*kN, kN, kD, nullptr, nullptr, 0, -1, 0);
    // gbase[b] = vg @ [Wih;Wx][:, :512]^T + [bih+bhh; 0]
    G(init_bf, 1536, Wfirst_bf, 512, gbase, nullptr, 2560, kB, 2560, kD, bias2560, nullptr, 0, -1, 0);
    // xall[t*128+b] = we @ [Wih;Wx][:, 512:]^T + gbase[b]
    G(we_bf, kE, Wlast_bf, 512, xall, nullptr, 2560, kT*kB, 2560, kE, nullptr, gbase, 2560, 127, 0);

    // ---- sequential LSTM recurrence only (one launch) ----
    scan_k<<<kB, 512, 0, stream>>>(initC, xall, Wrec_il, h2_bf, gtv_bf);

    // ---- deferred batched phases over M = T*B = 2560 rows ----
    // H = relu(h2 @ WH^T)           (fp32 + bf16)
    G(h2_bf, kD, WH_bf, kD, H_all, H_bfb, kD, kT*kB, kD, kD, nullptr, nullptr, 0, -1, 1);
    // s = relu(gtv @ Wc^T + bc)     (fp32 + bf16)
    G(gtv_bf, kD, Wc_bf, kD, s_all, s_bfb, kD, kT*kB, kD, kD, bc, nullptr, 0, -1, 1);
    // gH = H @ Wg^T   [2560,49]
    G(H_bfb, kD, Wg_bf, kD, gH_all, nullptr, kN, kT*kB, kN, kD, nullptr, nullptr, 0, -1, 0);
    // sWs = s @ Ws^T  [2560,49]
    G(s_bfb, kD, Ws_bf, kD, sWs_all, nullptr, kN, kT*kB, kN, kD, nullptr, nullptr, 0, -1, 0);
    // z / z2 / softmax / ctx / Hc  (+ attn output)
    attn_k<<<kT*kB, 256, 0, stream>>>(gH_all, sWs_all, H_all, s_all, Vf_bf, zbase, wh,
                                      Hc_bf, attn_out);
    // out = tanh(Hc @ Wfc^T + bfc)  (bf16 out)
    G(Hc_bf, kD, Wfc_bf, kD, nullptr, outbf, kD, kT*kB, kD, kD, bfc, nullptr, 0, -1, 2);

    // ---- logits (bf16) + log-softmax -> fp32 out ----
    G(outbf, kD, Wp_bf, kD, nullptr, logits_bf, kV, kT*kB, kV, kD, bp, nullptr, 0, -1, 0);
    logsoftmax_k<<<kB*kT, 256, 0, stream>>>(logits_bf, out0);
}

// Round 2
// 1099.364 us; speedup vs baseline: 1.2198x; 1.2198x over previous
//
#include <hip/hip_runtime.h>
#include <hip/hip_bf16.h>

// Problem dims
static const int kB = 128, kN = 49, kC = 2048, kD = 512, kE = 512, kV = 10000, kT = 20;

typedef __bf16 bf16x8 __attribute__((ext_vector_type(8)));
typedef float  f32x4v __attribute__((ext_vector_type(4)));
typedef _Float16 h8_t __attribute__((ext_vector_type(8)));
typedef _Float16 h2v_t __attribute__((ext_vector_type(2)));
typedef unsigned short u16;
typedef unsigned int u32;

#if defined(__has_builtin)
#if __has_builtin(__builtin_amdgcn_fdot2)
#define HAS_FDOT2 1
#endif
#endif
#ifndef HAS_FDOT2
#define HAS_FDOT2 0
#endif

#define AS1 __attribute__((address_space(1)))
#define AS3 __attribute__((address_space(3)))

__device__ __forceinline__ float sigmoidf_(float x){ return 1.f/(1.f+expf(-x)); }
__device__ __forceinline__ u16 f2b(float x){ __hip_bfloat16 h = __float2bfloat16(x); return *(u16*)&h; }
__device__ __forceinline__ float bu2f(u32 u){ u32 w = u << 16; union{u32 u; float f;} c; c.u = w; return c.f; }

// ================= bf16 MFMA NT GEMM =================
// C[M,N] = act(A[M,K]@W[N,K]^T + bias + add1[m&a1mask]), fp32 acc.
// C (fp32) and Cbf (bf16) both optional.
// REQUIRES: M % 128 == 0; W has >= ceil(N/128)*128 readable rows (padded
// workspace); staging uses global_load_lds width-16 (no bounds checks).
#define TBM 128
#define TBN 128
#define TBK 32

__global__ __launch_bounds__(256) void gemm_bf16(
    const u16* __restrict__ A, int lda,
    const u16* __restrict__ W, int ldw,
    float* __restrict__ C, u16* __restrict__ Cbf, int ldc,
    int M, int N, int K,
    const float* __restrict__ bias,
    const float* __restrict__ add1, int ld1, int a1mask,
    int act)
{
    __shared__ __align__(16) u16 As[TBM*TBK];
    __shared__ __align__(16) u16 Bs[TBN*TBK];
    const int tid = threadIdx.x;
    const int bm = blockIdx.y * TBM;
    const int bn = blockIdx.x * TBN;
    const int wave = tid >> 6, lane = tid & 63;
    const int wm = (wave >> 1) * 64, wn = (wave & 1) * 64;
    const int lm = lane & 15, quad = lane >> 4;
    f32x4v acc[4][4] = {};
    for (int k0 = 0; k0 < K; k0 += TBK) {
        // async global->LDS staging, 16B/lane, linear LDS dest per wave
        #pragma unroll
        for (int h = 0; h < 2; ++h) {
            const int slot = h*256 + tid;           // 0..511
            const int row = slot >> 2, kf = (slot & 3)*8;
            const int wbase = (h*256 + (tid & 448))*8;  // wave-uniform, u16 units
            __builtin_amdgcn_global_load_lds((const AS1 u32*)(A + (size_t)(bm + row)*lda + k0 + kf),
                                             (AS3 u32*)(As + wbase), 16, 0, 0);
            __builtin_amdgcn_global_load_lds((const AS1 u32*)(W + (size_t)(bn + row)*ldw + k0 + kf),
                                             (AS3 u32*)(Bs + wbase), 16, 0, 0);
        }
        __syncthreads();
        bf16x8 afr[4], bfr[4];
        #pragma unroll
        for (int i = 0; i < 4; ++i) afr[i] = *(const bf16x8*)&As[(wm + i*16 + lm)*TBK + quad*8];
        #pragma unroll
        for (int j = 0; j < 4; ++j) bfr[j] = *(const bf16x8*)&Bs[(wn + j*16 + lm)*TBK + quad*8];
        #pragma unroll
        for (int i = 0; i < 4; ++i)
            #pragma unroll
            for (int j = 0; j < 4; ++j)
                acc[i][j] = __builtin_amdgcn_mfma_f32_16x16x32_bf16(afr[i], bfr[j], acc[i][j], 0, 0, 0);
        __syncthreads();
    }
    #pragma unroll
    for (int i = 0; i < 4; ++i) {
        int mbase = bm + wm + i*16 + quad*4;
        #pragma unroll
        for (int j = 0; j < 4; ++j) {
            int n = bn + wn + j*16 + lm;
            if (n >= N) continue;
            float bv = bias ? bias[n] : 0.f;
            #pragma unroll
            for (int rr2 = 0; rr2 < 4; ++rr2) {
                int m = mbase + rr2;
                float v = acc[i][j][rr2] + bv;
                if (add1) v += add1[(size_t)(m & a1mask)*ld1 + n];
                if (act == 1) v = fmaxf(v, 0.f);
                else if (act == 2) v = tanhf(v);
                if (C)   C[(size_t)m*ldc + n] = v;
                if (Cbf) Cbf[(size_t)m*ldc + n] = f2b(v);
            }
        }
    }
}

// ================= conversion / prep kernels =================
// fp32 [rows][src_ld] (first K cols) -> bf16 [rows][K]
__global__ __launch_bounds__(256) void cvt2d_k(const float* __restrict__ src, int src_ld, int K,
                                               int rows, u16* __restrict__ dst){
    int idx = blockIdx.x*256 + threadIdx.x;
    int kc8 = K >> 3;
    if (idx >= rows*kc8) return;
    int rr = idx / kc8, kc = idx - rr*kc8;
    const float* p = src + (size_t)rr*src_ld + kc*8;
    f32x4v f0 = *(const f32x4v*)p, f1 = *(const f32x4v*)(p+4);
    union { u16 u[8]; uint4 v; } pk;
    pk.u[0]=f2b(f0[0]); pk.u[1]=f2b(f0[1]); pk.u[2]=f2b(f0[2]); pk.u[3]=f2b(f0[3]);
    pk.u[4]=f2b(f1[0]); pk.u[5]=f2b(f1[1]); pk.u[6]=f2b(f1[2]); pk.u[7]=f2b(f1[3]);
    *(uint4*)(dst + (size_t)rr*K + kc*8) = pk.v;
}

// fp32 [rows][src_ld] (K=512) -> f16 interleaved [k/8][Ntot][8] at row offset n_off
__global__ __launch_bounds__(256) void cvt_il_k(const float* __restrict__ src, int src_ld,
                                                int rows, int n_off, int Ntot,
                                                _Float16* __restrict__ dst){
    int idx = blockIdx.x*256 + threadIdx.x;
    if (idx >= rows*64) return;
    int rr = idx >> 6, kc = idx & 63;
    const float* p = src + (size_t)rr*src_ld + kc*8;
    f32x4v f0 = *(const f32x4v*)p, f1 = *(const f32x4v*)(p+4);
    h8_t o;
    o[0]=(_Float16)f0[0]; o[1]=(_Float16)f0[1]; o[2]=(_Float16)f0[2]; o[3]=(_Float16)f0[3];
    o[4]=(_Float16)f1[0]; o[5]=(_Float16)f1[1]; o[6]=(_Float16)f1[2]; o[7]=(_Float16)f1[3];
    *(h8_t*)&dst[((size_t)kc*Ntot + n_off + rr)*8] = o;
}

// bias2560 = [bih+bhh (2048); 0 (512)]; bcat3 = [bb|bhi|bmi]
__global__ __launch_bounds__(256) void bias_prep_k(const float* bih, const float* bhh,
                                                   const float* bb, const float* bhi, const float* bmi,
                                                   float* bias2560, float* bcat3){
    int i = blockIdx.x*256 + threadIdx.x;
    if (i < 2048) bias2560[i] = bih[i] + bhh[i];
    else if (i < 2560) bias2560[i] = 0.f;
    else if (i < 4096){
        int j = i - 2560;
        bcat3[j] = (j < 512) ? bb[j] : (j < 1024 ? bhi[j-512] : bmi[j-1024]);
    }
}

__global__ __launch_bounds__(256) void mean_k(const float* __restrict__ img, u16* __restrict__ meanp){
    int idx = blockIdx.x*256 + threadIdx.x;       // B*C
    int b = idx >> 11, c = idx & (kC-1);
    const float* p = img + (size_t)b*kN*kC + c;
    float s = 0.f;
    #pragma unroll
    for (int n = 0; n < kN; ++n) s += p[(size_t)n*kC];
    meanp[idx] = f2b(s * (1.f/(float)kN));
}

// we[t*B+b][e] bf16
__global__ __launch_bounds__(256) void emb_gather_k(const int* __restrict__ target,
                                                    const float* __restrict__ emb,
                                                    u16* __restrict__ we){
    int idx = blockIdx.x*256 + threadIdx.x;       // T*B*E
    int e = idx & (kE-1);
    int rr = idx >> 9;                            // t*B + b
    int b = rr & 127, t = rr >> 7;
    float v = 0.f;
    if (t > 0){ int tok = target[b*kT + (t-1)]; v = emb[(size_t)tok*kE + e]; }
    we[idx] = f2b(v);
}

// ================= persistent per-batch LSTM recurrence (gates only) =================
// 1024 threads: thread = (out in [0,512), kh in {0,1}); kh splits K.
// Partial sums combined via LDS; pointwise on kh==0 threads.
__device__ __forceinline__ float dot8f(h8_t a, h8_t b, float c){
#if HAS_FDOT2
    const h2v_t* ap = (const h2v_t*)&a;
    const h2v_t* bp = (const h2v_t*)&b;
    c = __builtin_amdgcn_fdot2(ap[0], bp[0], c, false);
    c = __builtin_amdgcn_fdot2(ap[1], bp[1], c, false);
    c = __builtin_amdgcn_fdot2(ap[2], bp[2], c, false);
    c = __builtin_amdgcn_fdot2(ap[3], bp[3], c, false);
#else
    #pragma unroll
    for (int i = 0; i < 8; ++i) c = fmaf((float)a[i], (float)b[i], c);
#endif
    return c;
}

__global__ __launch_bounds__(1024, 1) void scan_k(
    const float* __restrict__ initC,       // [128][1536] vg|h0|m0 (fp32)
    const float* __restrict__ xall,        // [20][128][2560]
    const _Float16* __restrict__ Wrec,     // il [64][2560][8]
    u16* __restrict__ h2_bf,               // [20*128][512] bf16 (row t*128+b)
    u16* __restrict__ gtv_bf)              // [20*128][512] bf16
{
    const int b = blockIdx.x, tid = threadIdx.x;
    const int out = tid & 511, kh = tid >> 9;
    __shared__ __align__(16) _Float16 sh[512];     // h (f16)
    __shared__ float spart[512][5];

    if (tid < 512) sh[tid] = (_Float16)initC[(size_t)b*1536 + 512 + tid];
    float m_reg = (kh == 0) ? initC[(size_t)b*1536 + 1024 + out] : 0.f;
    __syncthreads();

    for (int t = 0; t < kT; ++t){
        float acc[5] = {0.f, 0.f, 0.f, 0.f, 0.f};
        const int kc0 = kh*32;
        #pragma unroll 2
        for (int kc = kc0; kc < kc0 + 32; ++kc){
            h8_t hv = *(const h8_t*)&sh[kc*8];
            const _Float16* wb = Wrec + (size_t)kc*2560*8;
            #pragma unroll
            for (int j = 0; j < 5; ++j){
                h8_t wv = *(const h8_t*)&wb[(size_t)(out + 512*j)*8];
                acc[j] = dot8f(hv, wv, acc[j]);
            }
        }
        __syncthreads();                      // all GEMV reads of sh done
        if (kh == 1){
            #pragma unroll
            for (int j = 0; j < 5; ++j) spart[out][j] = acc[j];
        }
        __syncthreads();
        if (kh == 0){
            const float* xrow = xall + ((size_t)t*kB + b)*2560;
            #pragma unroll
            for (int j = 0; j < 5; ++j) acc[j] += spart[out][j] + xrow[out + 512*j];
            float i_g = sigmoidf_(acc[0]);
            float f_g = sigmoidf_(acc[1]);
            float g_g = tanhf(acc[2]);
            float o_g = sigmoidf_(acc[3]);
            m_reg = f_g*m_reg + i_g*g_g;
            float tm = tanhf(m_reg);
            float h2v = o_g*tm;
            float gtvv = sigmoidf_(acc[4])*tm;
            sh[out] = (_Float16)h2v;
            size_t row = (size_t)t*kB + b;
            h2_bf[row*512 + out] = f2b(h2v);
            gtv_bf[row*512 + out] = f2b(gtvv);
        }
        __syncthreads();
    }
}

// ================= batched attention kernel: one block per (t,b) row =================
__global__ __launch_bounds__(256) void attn_k(
    const float* __restrict__ gH_all,      // [2560][49]
    const float* __restrict__ sWs_all,     // [2560][49]
    const float* __restrict__ H_all,       // [2560][512] fp32
    const float* __restrict__ s_all,       // [2560][512] fp32
    const u16* __restrict__ Vf_bf,         // [128*49][512] bf16
    const float* __restrict__ zbase,       // [128][49][49]
    const float* __restrict__ wh,          // [49]
    u16* __restrict__ Hc_bf,               // [2560][512] bf16
    float* __restrict__ attn_out)          // [128][20][49] fp32
{
    const int r = blockIdx.x, tid = threadIdx.x;   // r = t*128 + b
    const int b = r & 127, t = r >> 7;
    __shared__ float sgH[52], ssWs[52], swh[52], sz[52], salpha[52];

    if (tid < 49){
        sgH[tid]  = gH_all [(size_t)r*49 + tid];
        ssWs[tid] = sWs_all[(size_t)r*49 + tid];
        swh[tid]  = wh[tid];
    }
    __syncthreads();
    if (tid < 49){
        const float* zb = zbase + (size_t)b*2401 + (size_t)tid*49;
        float a = 0.f;
        #pragma unroll
        for (int k = 0; k < 49; ++k) a += tanhf(zb[k] + sgH[k]) * swh[k];
        sz[tid] = a;
    }
    if (tid == 64){
        float a = 0.f;
        #pragma unroll
        for (int k = 0; k < 49; ++k) a += tanhf(ssWs[k] + sgH[k]) * swh[k];
        sz[49] = a;
    }
    __syncthreads();
    // softmax over 50 on wave 0
    if (tid < 64){
        float val = (tid < 50) ? sz[tid] : -1e30f;
        float mx = val;
        #pragma unroll
        for (int o = 32; o > 0; o >>= 1) mx = fmaxf(mx, __shfl_xor(mx, o));
        float e = (tid < 50) ? __expf(val - mx) : 0.f;
        float ssum = e;
        #pragma unroll
        for (int o = 32; o > 0; o >>= 1) ssum += __shfl_xor(ssum, o);
        float a = e/ssum;
        if (tid < 50) salpha[tid] = a;
        if (tid < 49) attn_out[((size_t)b*kT + t)*kN + tid] = a;
    }
    __syncthreads();
    // ctx + Hc (coalesced across d)
    for (int d = tid; d < 512; d += 256){
        float a = salpha[49] * s_all[(size_t)r*512 + d];
        const u16* vf = Vf_bf + (size_t)b*49*512 + d;
        #pragma unroll
        for (int n = 0; n < 49; ++n) a = fmaf(salpha[n], bu2f(vf[(size_t)n*512]), a);
        Hc_bf[(size_t)r*512 + d] = f2b(H_all[(size_t)r*512 + d] + a);
    }
}

// ================= log-softmax: read bf16 logits row (t*128+b), write fp32 row (b*20+t) =================
__global__ __launch_bounds__(256) void logsoftmax_k(const u16* __restrict__ logits_bf,
                                                    float* __restrict__ out0)
{
    const int r = blockIdx.x, tid = threadIdx.x;   // r = b*20+t
    const int b = r / 20, t = r - b*20;
    const u16* L = logits_bf + (size_t)(t*kB + b)*kV;
    __shared__ float rm[256], rs[256];
    float m = -1e30f, s = 0.f;
    for (int c = tid; c < kV/8; c += 256){
        uint4 v = *(const uint4*)(L + c*8);
        u32 w[4] = {v.x, v.y, v.z, v.w};
        #pragma unroll
        for (int j = 0; j < 4; ++j){
            float x0 = bu2f(w[j] & 0xffff), x1 = bu2f(w[j] >> 16);
            float nm = fmaxf(m, fmaxf(x0, x1));
            s = s*__expf(m - nm) + __expf(x0 - nm) + __expf(x1 - nm);
            m = nm;
        }
    }
    rm[tid] = m; rs[tid] = s; __syncthreads();
    for (int st = 128; st > 0; st >>= 1){
        if (tid < st){
            float m2 = rm[tid + st], s2 = rs[tid + st];
            float nm = fmaxf(rm[tid], m2);
            rs[tid] = rs[tid]*__expf(rm[tid] - nm) + s2*__expf(m2 - nm);
            rm[tid] = nm;
        }
        __syncthreads();
    }
    float lse = rm[0] + logf(rs[0]);
    float* D = out0 + (size_t)r*kV;
    for (int c = tid; c < kV/8; c += 256){
        uint4 v = *(const uint4*)(L + c*8);
        u32 w[4] = {v.x, v.y, v.z, v.w};
        f32x4v o0, o1;
        o0[0]=bu2f(w[0]&0xffff)-lse; o0[1]=bu2f(w[0]>>16)-lse;
        o0[2]=bu2f(w[1]&0xffff)-lse; o0[3]=bu2f(w[1]>>16)-lse;
        o1[0]=bu2f(w[2]&0xffff)-lse; o1[1]=bu2f(w[2]>>16)-lse;
        o1[2]=bu2f(w[3]&0xffff)-lse; o1[3]=bu2f(w[3]>>16)-lse;
        *(f32x4v*)(D + c*8) = o0;
        *(f32x4v*)(D + c*8 + 4) = o1;
    }
}

extern "C" void kernel_launch(void* const* d_in, const int* in_sizes, int n_in,
                              void* d_out, int out_size, void* d_ws, size_t ws_size,
                              hipStream_t stream)
{
    const float* img   = (const float*)d_in[0];
    const int*   target= (const int*)  d_in[1];
    const float* emb   = (const float*)d_in[2];
    const float* Wa    = (const float*)d_in[3];
    const float* ba    = (const float*)d_in[4];
    const float* Wb    = (const float*)d_in[5];
    const float* bb    = (const float*)d_in[6];
    const float* Whi   = (const float*)d_in[7];
    const float* bhi   = (const float*)d_in[8];
    const float* Wmi   = (const float*)d_in[9];
    const float* bmi   = (const float*)d_in[10];
    const float* Wih   = (const float*)d_in[11];
    const float* bih   = (const float*)d_in[12];
    const float* Whh   = (const float*)d_in[13];
    const float* bhh   = (const float*)d_in[14];
    const float* Wv    = (const float*)d_in[15];
    const float* Wg    = (const float*)d_in[16];
    const float* wh    = (const float*)d_in[17];
    const float* W_H   = (const float*)d_in[18];
    const float* Wx    = (const float*)d_in[19];
    const float* Wh2   = (const float*)d_in[20];
    const float* Wsm   = (const float*)d_in[21];
    const float* Wc    = (const float*)d_in[22];
    const float* bc    = (const float*)d_in[23];
    const float* Wfc   = (const float*)d_in[24];
    const float* bfc   = (const float*)d_in[25];
    const float* Wp    = (const float*)d_in[26];
    const float* bp    = (const float*)d_in[27];
    (void)in_sizes; (void)n_in; (void)out_size; (void)ws_size;

    float* out0 = (float*)d_out;                       // [B*T, V] logprobs (row b*20+t)
    float* attn_out = out0 + (size_t)kB*kT*kV;         // [B, T, N]

    char* base = (char*)d_ws;
    size_t off = 0;
    auto alloc = [&](size_t bytes)->char*{
        char* p = base + off;
        off += ((bytes + 255) & ~(size_t)255);
        return p;
    };
    // fixed region (W arrays padded to 128-row multiples for unchecked staging)
    u16* Wa_bf     = (u16*)alloc((size_t)kD*kC*2);
    u16* Winit_bf  = (u16*)alloc((size_t)1536*kC*2);
    u16* Wv_bf     = (u16*)alloc((size_t)128*kD*2);           // 49 -> 128 rows
    u16* Wp_bf     = (u16*)alloc((size_t)10112*kD*2);         // 10000 -> 10112 rows
    u16* Wfirst_bf = (u16*)alloc((size_t)2560*512*2); // [Wih[:, :512]; Wx[:, :512]]
    u16* Wlast_bf  = (u16*)alloc((size_t)2560*512*2); // [Wih[:, 512:]; Wx[:, 512:]]
    _Float16* Wrec_il = (_Float16*)alloc((size_t)2560*512*2);
    u16* WH_bf     = (u16*)alloc((size_t)512*512*2);
    u16* Wc_bf     = (u16*)alloc((size_t)512*512*2);
    u16* Wg_bf     = (u16*)alloc((size_t)128*512*2);          // 49 -> 128 rows
    u16* Ws_bf     = (u16*)alloc((size_t)128*512*2);          // 49 -> 128 rows
    u16* Wfc_bf    = (u16*)alloc((size_t)512*512*2);
    float* bias2560 = (float*)alloc(2560*4);
    float* bcat3    = (float*)alloc(1536*4);
    u16* meanb_bf   = (u16*)alloc((size_t)kB*kC*2);
    float* initC    = (float*)alloc((size_t)kB*1536*4);
    u16* init_bf    = (u16*)alloc((size_t)kB*1536*2);
    u16* Vf_bf      = (u16*)alloc((size_t)kB*kN*kD*2);
    float* zbase    = (float*)alloc((size_t)kB*kN*kN*4);
    u16* we_bf      = (u16*)alloc((size_t)kT*kB*kE*2);
    float* gbase    = (float*)alloc((size_t)kB*2560*4);
    u16* outbf      = (u16*)alloc((size_t)kT*kB*kD*2);
    u16* h2_bf      = (u16*)alloc((size_t)kT*kB*kD*2);
    u16* gtv_bf     = (u16*)alloc((size_t)kT*kB*kD*2);

    // dynamic region, time-multiplexed:
    //  phase 1 (prep):       img_bf [0, 25.7MB) ; xall [25.7, 51.9MB)
    //  phase 2 (post-scan):  deferred-phase buffers alias img_bf region (img dead after Vf GEMM)
    //  phase 3 (logits):     logits_bf [0, 51.2MB) (all phase buffers dead after D-GEMM)
    char* dyn = base + off;
    u16* img_bf    = (u16*)dyn;
    float* xall    = (float*)(dyn + (((size_t)kB*kN*kC*2 + 255) & ~(size_t)255));
    u16* logits_bf = (u16*)dyn;
    size_t poff = 0;
    auto palloc = [&](size_t bytes)->char*{
        char* p = dyn + poff;
        poff += ((bytes + 255) & ~(size_t)255);
        return p;
    };
    float* H_all   = (float*)palloc((size_t)kT*kB*kD*4);
    float* s_all   = (float*)palloc((size_t)kT*kB*kD*4);
    u16*   H_bfb   = (u16*)  palloc((size_t)kT*kB*kD*2);
    u16*   s_bfb   = (u16*)  palloc((size_t)kT*kB*kD*2);
    float* gH_all  = (float*)palloc((size_t)kT*kB*kN*4);
    float* sWs_all = (float*)palloc((size_t)kT*kB*kN*4);
    u16*   Hc_bf   = (u16*)  palloc((size_t)kT*kB*kD*2);
    // total phase buffers ~19.4MB < img_bf's 25.7MB: no overlap with xall.

    auto G = [&](const u16* A, int lda, const u16* W, int ldw,
                 float* C, u16* Cbf, int ldc, int M, int N, int K,
                 const float* bias, const float* a1, int l1, int a1mask, int act){
        dim3 g((N + TBN - 1)/TBN, (M + TBM - 1)/TBM);
        gemm_bf16<<<g, 256, 0, stream>>>(A, lda, W, ldw, C, Cbf, ldc, M, N, K,
                                         bias, a1, l1, a1mask, act);
    };
    auto CV = [&](const float* src, int src_ld, int K, int rows, u16* dst){
        int n = rows*(K/8);
        cvt2d_k<<<(n + 255)/256, 256, 0, stream>>>(src, src_ld, K, rows, dst);
    };
    auto IL = [&](const float* src, int rows, int n_off, int Ntot, _Float16* dst){
        int n = rows*64;
        cvt_il_k<<<(n + 255)/256, 256, 0, stream>>>(src, 512, rows, n_off, Ntot, dst);
    };

    // ---- prep ----
    bias_prep_k<<<16, 256, 0, stream>>>(bih, bhh, bb, bhi, bmi, bias2560, bcat3);
    mean_k<<<kB*kC/256, 256, 0, stream>>>(img, meanb_bf);
    emb_gather_k<<<kT*kB*kE/256, 256, 0, stream>>>(target, emb, we_bf);
    CV(img, kC, kC, kB*kN, img_bf);
    CV(Wa,  kC, kC, kD, Wa_bf);
    CV(Wb,  kC, kC, kD, Winit_bf);
    CV(Whi, kC, kC, kD, Winit_bf + (size_t)512*kC);
    CV(Wmi, kC, kC, kD, Winit_bf + (size_t)1024*kC);
    CV(Wv,  kD, kD, kN, Wv_bf);
    CV(Wp,  kD, kD, kV, Wp_bf);
    CV(Wih,       1024, 512, 2048, Wfirst_bf);
    CV(Wx,        1024, 512, 512,  Wfirst_bf + (size_t)2048*512);
    CV(Wih + 512, 1024, 512, 2048, Wlast_bf);
    CV(Wx  + 512, 1024, 512, 512,  Wlast_bf + (size_t)2048*512);
    CV(W_H, 512, 512, 512, WH_bf);
    CV(Wc,  512, 512, 512, Wc_bf);
    CV(Wg,  512, 512, kN,  Wg_bf);
    CV(Wsm, 512, 512, kN,  Ws_bf);
    CV(Wfc, 512, 512, 512, Wfc_bf);
    IL(Whh, 2048, 0,    2560, Wrec_il);
    IL(Wh2, 512,  2048, 2560, Wrec_il);

    // ---- precompute GEMMs ----
    // [vg|h0|m0] = relu(mean @ [Wb;Whi;Wmi]^T + bcat3)
    G(meanb_bf, kC, Winit_bf, kC, initC, init_bf, 1536, kB, 1536, kC, bcat3, nullptr, 0, -1, 1);
    // Vf = relu(img @ Wa^T + ba)  (bf16 out only)
    G(img_bf, kC, Wa_bf, kC, nullptr, Vf_bf, kD, kB*kN, kD, kC, ba, nullptr, 0, -1, 1);
    // zbase = Vf @ Wv^T (fp32)
    G(Vf_bf, kD, Wv_bf, kD, zbase, nullptr, kN, kB*kN, kN, kD, nullptr, nullptr, 0, -1, 0);
    // gbase[b] = vg @ [Wih;Wx][:, :512]^T + [bih+bhh; 0]
    G(init_bf, 1536, Wfirst_bf, 512, gbase, nullptr, 2560, kB, 2560, kD, bias2560, nullptr, 0, -1, 0);
    // xall[t*128+b] = we @ [Wih;Wx][:, 512:]^T + gbase[b]
    G(we_bf, kE, Wlast_bf, 512, xall, nullptr, 2560, kT*kB, 2560, kE, nullptr, gbase, 2560, 127, 0);

    // ---- sequential LSTM recurrence only (one launch) ----
    scan_k<<<kB, 1024, 0, stream>>>(initC, xall, Wrec_il, h2_bf, gtv_bf);

    // ---- deferred batched phases over M = T*B = 2560 rows ----
    // H = relu(h2 @ WH^T)           (fp32 + bf16)
    G(h2_bf, kD, WH_bf, kD, H_all, H_bfb, kD, kT*kB, kD, kD, nullptr, nullptr, 0, -1, 1);
    // s = relu(gtv @ Wc^T + bc)     (fp32 + bf16)
    G(gtv_bf, kD, Wc_bf, kD, s_all, s_bfb, kD, kT*kB, kD, kD, bc, nullptr, 0, -1, 1);
    // gH = H @ Wg^T   [2560,49]
    G(H_bfb, kD, Wg_bf, kD, gH_all, nullptr, kN, kT*kB, kN, kD, nullptr, nullptr, 0, -1, 0);
    // sWs = s @ Ws^T  [2560,49]
    G(s_bfb, kD, Ws_bf, kD, sWs_all, nullptr, kN, kT*kB, kN, kD, nullptr, nullptr, 0, -1, 0);
    // z / z2 / softmax / ctx / Hc  (+ attn output)
    attn_k<<<kT*kB, 256, 0, stream>>>(gH_all, sWs_all, H_all, s_all, Vf_bf, zbase, wh,
                                      Hc_bf, attn_out);
    // out = tanh(Hc @ Wfc^T + bfc)  (bf16 out)
    G(Hc_bf, kD, Wfc_bf, kD, nullptr, outbf, kD, kT*kB, kD, kD, bfc, nullptr, 0, -1, 2);

    // ---- logits (bf16) + log-softmax -> fp32 out ----
    G(outbf, kD, Wp_bf, kD, nullptr, logits_bf, kV, kT*kB, kV, kD, bp, nullptr, 0, -1, 0);
    logsoftmax_k<<<kB*kT, 256, 0, stream>>>(logits_bf, out0);
}